// Round 10
// baseline (402.739 us; speedup 1.0000x reference)
//
#include <hip/hip_runtime.h>
#include <math.h>

// Tsit5 tableau
#define A21f 0.161f
#define A31f -0.008480655492356989f
#define A32f 0.335480655492357f
#define A41f 2.8971530571054935f
#define A42f -6.359448489975075f
#define A43f 4.3622954328695815f
#define A51f 5.325864828439257f
#define A52f -11.748883564062828f
#define A53f 7.4955393428898365f
#define A54f -0.09249506636175525f
#define A61f 5.86145544294642f
#define A62f -12.92096931784711f
#define A63f 8.159367898576159f
#define A64f -0.071584973281401f
#define A65f -0.028269050394068383f
#define B1f 0.09646076681806523f
#define B2f 0.01f
#define B3f 0.4798896504144996f
#define B4f 1.379008574103742f
#define B5f -3.290069515436081f
#define B6f 2.324710524099774f
#define E1f -0.00178001105222577714f
#define E2f -0.0008164344596567469f
#define E3f 0.007880878010261995f
#define E4f -0.1447110071732629f
#define E5f 0.5823571654525552f
#define E6f -0.45808210592918697f
#define E7f 0.015151515151515152f

#define WPB 4  // waves per block

#if defined(__has_attribute)
#if __has_attribute(amdgpu_agpr_alloc)
#define AGPR0 __attribute__((amdgpu_agpr_alloc(0)))
#else
#define AGPR0
#endif
#else
#define AGPR0
#endif

// Fused rotate+FMA: acc += (row_ror:N of v) * w — ONE VALU inst (VOP2 DPP).
#define FMAC_RR(acc, v, w, N)                                              \
    asm("v_fmac_f32_dpp %0, %1, %2 row_ror:" #N " row_mask:0xf bank_mask:0xf" \
        : "+v"(acc) : "v"(v), "v"(w))

// s = ror_N(s) + s  (in-row rotation add, VALU pipe)
#define ADD_RR(s, N)                                                       \
    asm("v_add_f32_dpp %0, %1, %0 row_ror:" #N " row_mask:0xf bank_mask:0xf" \
        : "+v"(s) : "v"(s))

// Butterfly SUM x + x[lane^16] on the VALU pipe (gfx950 permlane16_swap).
// Two copies of x, swap 16-lane groups between them -> each lane holds
// {own, partner} across (a,b); a+b is bitwise-commutative, so this is
// bitwise identical to x + __shfl_xor(x,16) under ANY half-swap direction.
// s_nop padding: defensive waitstates around an instruction the compiler's
// hazard recognizer can't see into.
__device__ __forceinline__ float psum16(float x) {
    float a, b;
    asm("v_mov_b32 %0, %2\n\t"
        "v_mov_b32 %1, %2\n\t"
        "s_nop 0\n\t"
        "v_permlane16_swap_b32 %0, %1\n\t"
        "s_nop 0"
        : "=&v"(a), "=&v"(b) : "v"(x));
    return a + b;
}
// Same for x + x[lane^32] (swap 32-lane halves between two regs).
__device__ __forceinline__ float psum32(float x) {
    float a, b;
    asm("v_mov_b32 %0, %2\n\t"
        "v_mov_b32 %1, %2\n\t"
        "s_nop 0\n\t"
        "v_permlane32_swap_b32 %0, %1\n\t"
        "s_nop 0"
        : "=&v"(a), "=&v"(b) : "v"(x));
    return a + b;
}

// Half-dots: 8-deep fmac chains.
#define DOT8_LO(acc, W, v) do {          \
    acc = fmaf((W)[0], (v), acc);        \
    FMAC_RR(acc, v, (W)[1], 1);          \
    FMAC_RR(acc, v, (W)[2], 2);          \
    FMAC_RR(acc, v, (W)[3], 3);          \
    FMAC_RR(acc, v, (W)[4], 4);          \
    FMAC_RR(acc, v, (W)[5], 5);          \
    FMAC_RR(acc, v, (W)[6], 6);          \
    FMAC_RR(acc, v, (W)[7], 7);          \
} while (0)
#define DOT8_HI(acc, W, v) do {          \
    FMAC_RR(acc, v, (W)[8], 8);          \
    FMAC_RR(acc, v, (W)[9], 9);          \
    FMAC_RR(acc, v, (W)[10], 10);        \
    FMAC_RR(acc, v, (W)[11], 11);        \
    FMAC_RR(acc, v, (W)[12], 12);        \
    FMAC_RR(acc, v, (W)[13], 13);        \
    FMAC_RR(acc, v, (W)[14], 14);        \
    FMAC_RR(acc, v, (W)[15], 15);        \
} while (0)

// softplus(x) = max(x,0) + ln2 * log2(1 + 2^(-|x|*log2e))  (hw exp2/log2)
__device__ __forceinline__ float sp(float x) {
    float t = exp2f(-fabsf(x) * 1.44269504088896341f);
    return fmaxf(x, 0.0f) + 0.69314718055994531f * __log2f(1.0f + t);
}

// DUAL-TRAJECTORY wave (round 9) + all butterfly SUMS moved DS -> VALU via
// permlane swaps (round 10). Only the h2 half-exchange remains on DS.
__global__ __launch_bounds__(256)
__attribute__((amdgpu_waves_per_eu(2, 2))) AGPR0
void ode_kernel(const float* __restrict__ x0s,
                const float* __restrict__ W1, const float* __restrict__ b1,
                const float* __restrict__ W2, const float* __restrict__ b2,
                const float* __restrict__ W3, const float* __restrict__ b3,
                const void* __restrict__ Tptr,
                float* __restrict__ out, int out_size, int B)
{
    const int wave = threadIdx.x >> 6;
    const int lane = threadIdx.x & 63;
    const int wid  = blockIdx.x * WPB + wave;
    const int trA  = wid * 2;
    const int trB  = wid * 2 + 1;
    if (trA >= B) return;
    const bool hasB = (trB < B);

    const int p = lane & 15;   // position within 16-lane DPP row
    const int g = lane >> 4;   // row-group 0..3
    const int godd = g & 1;
    const int jh = g >> 1;     // layer-2 input half

    // ---- one-time per-lane weight gathers in DPP-rotated order ----
    float W1a[16], W1b[16], W2r[16], W3a[16], W3b[16];
    const int r2 = p + 16 * godd;
#pragma unroll
    for (int k = 0; k < 16; ++k) {
        const int c = (p + k) & 15;
        W1a[k] = W1[p * 64 + 16 * g + c];
        W1b[k] = W1[(16 + p) * 64 + 16 * g + c];
        W2r[k] = W2[r2 * 32 + 16 * jh + c];
        W3a[k] = W3[lane * 32 + c];
        W3b[k] = W3[lane * 32 + 16 + c];
    }
#pragma unroll
    for (int k = 0; k < 16; ++k) {
        asm("" : "+v"(W1a[k]));
        asm("" : "+v"(W1b[k]));
        asm("" : "+v"(W2r[k]));
        asm("" : "+v"(W3a[k]));
        asm("" : "+v"(W3b[k]));
    }
    const float b1a = b1[p], b1b = b1[p + 16];
    const float b2r = b2[r2], b3r = b3[lane];

    // Dual f. Per-trajectory arithmetic is bitwise identical to rounds 7/9
    // (butterfly operand pairs unchanged; FP add commutes bitwise).
    // INVARIANT: reductions are symmetric -> lane-uniform accept/break flags.
    auto fd = [&](float uA, float uB, float& rA, float& rB) {
        float aA0 = 0.f, aA1 = 0.f, aA2 = 0.f, aA3 = 0.f;
        float aB0 = 0.f, aB1 = 0.f, aB2 = 0.f, aB3 = 0.f;
        DOT8_LO(aA0, W1a, uA);
        DOT8_LO(aB0, W1a, uB);
        DOT8_HI(aA1, W1a, uA);
        DOT8_HI(aB1, W1a, uB);
        DOT8_LO(aA2, W1b, uA);
        DOT8_LO(aB2, W1b, uB);
        DOT8_HI(aA3, W1b, uA);
        DOT8_HI(aB3, W1b, uB);
        float a1aA = psum32(psum16(aA0 + aA1));
        float a1bA = psum32(psum16(aA2 + aA3));
        float a1aB = psum32(psum16(aB0 + aB1));
        float a1bB = psum32(psum16(aB2 + aB3));
        float h1AA = sp(a1aA + b1a);   // traj A: h1[p]
        float h1BA = sp(a1bA + b1b);   // traj A: h1[16+p]
        float h1AB = sp(a1aB + b1a);   // traj B: h1[p]
        float h1BB = sp(a1bB + b1b);   // traj B: h1[16+p]
        float SA = jh ? h1BA : h1AA;
        float SB = jh ? h1BB : h1AB;
        float a2A0 = 0.f, a2A1 = 0.f, a2B0 = 0.f, a2B1 = 0.f;
        DOT8_LO(a2A0, W2r, SA);
        DOT8_LO(a2B0, W2r, SB);
        DOT8_HI(a2A1, W2r, SA);
        DOT8_HI(a2B1, W2r, SB);
        float a2A = psum32(a2A0 + a2A1);
        float a2B = psum32(a2B0 + a2B1);
        float h2vA = sp(a2A + b2r);
        float h2vB = sp(a2B + b2r);
        // true EXCHANGE (need partner value, not sum) — stays on DS
        float oA = __shfl_xor(h2vA, 16);
        float oB = __shfl_xor(h2vB, 16);
        float h2AA = godd ? oA : h2vA;     // A: h2[p]
        float h2BA = godd ? h2vA : oA;     // A: h2[16+p]
        float h2AB = godd ? oB : h2vB;     // B: h2[p]
        float h2BB = godd ? h2vB : oB;     // B: h2[16+p]
        float cA0 = 0.f, cA1 = 0.f, dA0 = 0.f, dA1 = 0.f;
        float cB0 = 0.f, cB1 = 0.f, dB0 = 0.f, dB1 = 0.f;
        DOT8_LO(cA0, W3a, h2AA);
        DOT8_LO(cB0, W3a, h2AB);
        DOT8_HI(cA1, W3a, h2AA);
        DOT8_HI(cB1, W3a, h2AB);
        DOT8_LO(dA0, W3b, h2BA);
        DOT8_LO(dB0, W3b, h2BB);
        DOT8_HI(dA1, W3b, h2BA);
        DOT8_HI(dB1, W3b, h2BB);
        rA = ((cA0 + cA1) + (dA0 + dA1)) + b3r;
        rB = ((cB0 + cB1) + (dB0 + dB1)) + b3r;
    };

    int ti = *(const int*)Tptr;
    float Tf = (ti > 0 && ti < 1000000) ? (float)ti : *(const float*)Tptr;
    const float ts_step = Tf / 10.0f;

    float yA = x0s[trA * 64 + lane];
    float yB = hasB ? x0s[trB * 64 + lane] : 0.0f;
    out[trA * 704 + lane] = yA;
    if (hasB) out[trB * 704 + lane] = yB;

    float tA = 0.0f, tB = hasB ? 0.0f : Tf;
    float dtA = 1e-3f, dtB = 1e-3f;
    int nA = 0, nB = 0;

    float k1A, k1B;
    fd(yA, yB, k1A, k1B);  // FSAL seed

    for (int iv = 1; iv <= 10; ++iv) {
        const float t_target = (iv == 10) ? Tf : ts_step * (float)iv;
        for (int it = 0; it < 64; ++it) {
            const float remA = t_target - tA;
            const float remB = t_target - tB;
            const bool actA = remA > 1e-12f;
            const bool actB = remB > 1e-12f;
            if (!actA && !actB) break;   // wave-uniform
            const float hA = fminf(dtA, fmaxf(remA, 0.0f));
            const float hB = fminf(dtB, fmaxf(remB, 0.0f));

            float k2A, k2B, k3A, k3B, k4A, k4B, k5A, k5B, k6A, k6B, k7A, k7B;
            float aA, aB;
            aA = yA + hA * (A21f * k1A);
            aB = yB + hB * (A21f * k1B);
            fd(aA, aB, k2A, k2B);
            aA = yA + hA * (A31f * k1A + A32f * k2A);
            aB = yB + hB * (A31f * k1B + A32f * k2B);
            fd(aA, aB, k3A, k3B);
            aA = yA + hA * (A41f * k1A + A42f * k2A + A43f * k3A);
            aB = yB + hB * (A41f * k1B + A42f * k2B + A43f * k3B);
            fd(aA, aB, k4A, k4B);
            aA = yA + hA * (A51f * k1A + A52f * k2A + A53f * k3A + A54f * k4A);
            aB = yB + hB * (A51f * k1B + A52f * k2B + A53f * k3B + A54f * k4B);
            fd(aA, aB, k5A, k5B);
            aA = yA + hA * (A61f * k1A + A62f * k2A + A63f * k3A + A64f * k4A + A65f * k5A);
            aB = yB + hB * (A61f * k1B + A62f * k2B + A63f * k3B + A64f * k4B + A65f * k5B);
            fd(aA, aB, k6A, k6B);
            float y5A = yA + hA * (B1f * k1A + B2f * k2A + B3f * k3A + B4f * k4A + B5f * k5A + B6f * k6A);
            float y5B = yB + hB * (B1f * k1B + B2f * k2B + B3f * k3B + B4f * k4B + B5f * k5B + B6f * k6B);
            fd(y5A, y5B, k7A, k7B);
            float errA = hA * (E1f * k1A + E2f * k2A + E3f * k3A + E4f * k4A + E5f * k5A + E6f * k6A + E7f * k7A);
            float errB = hB * (E1f * k1B + E2f * k2B + E3f * k3B + E4f * k4B + E5f * k5B + E6f * k6B + E7f * k7B);

            float sclA = 1e-6f + 1e-3f * fmaxf(fabsf(yA), fabsf(y5A));
            float sclB = 1e-6f + 1e-3f * fmaxf(fabsf(yB), fabsf(y5B));
            float rA_ = errA / sclA;
            float rB_ = errB / sclB;
            float sA = rA_ * rA_;
            float sB = rB_ * rB_;
            // Stages 32,16: permlane sums (bitwise == shfl_xor butterfly).
            // Stages 8,4,2,1: DPP ror adds — partner (p+m)%16 is in the same
            // bitwise-equal class as p^m once s has period 2m (induction from
            // the 32/16 stages), so result is bitwise == xor butterfly and
            // lane-uniform (round-6 invariant holds).
            sA = psum32(sA); sB = psum32(sB);
            sA = psum16(sA); sB = psum16(sB);
            ADD_RR(sA, 8);  ADD_RR(sB, 8);
            ADD_RR(sA, 4);  ADD_RR(sB, 4);
            ADD_RR(sA, 2);  ADD_RR(sB, 2);
            ADD_RR(sA, 1);  ADD_RR(sB, 1);
            float enA = fmaxf(sqrtf(sA * (1.0f / 64.0f)), 1e-10f);
            float enB = fmaxf(sqrtf(sB * (1.0f / 64.0f)), 1e-10f);

            bool accA = enA <= 1.0f;
            bool accB = enB <= 1.0f;
            float facA = fminf(fmaxf(0.9f * exp2f(-0.2f * __log2f(enA)), 0.1f), 5.0f);
            float facB = fminf(fmaxf(0.9f * exp2f(-0.2f * __log2f(enB)), 0.1f), 5.0f);

            if (actA) {
                if (accA) { tA += hA; yA = y5A; k1A = k7A; }
                dtA = fmaxf(hA * facA, 1e-8f);
                ++nA;
            }
            if (actB) {
                if (accB) { tB += hB; yB = y5B; k1B = k7B; }
                dtB = fmaxf(hB * facB, 1e-8f);
                ++nB;
            }
        }
        out[trA * 704 + iv * 64 + lane] = yA;
        if (hasB) out[trB * 704 + iv * 64 + lane] = yB;
    }

    if (lane == 0) atomicAdd(out + (out_size - 1), (float)(nA + (hasB ? nB : 0)));
}

__global__ void init_n(float* p) { *p = 0.0f; }

extern "C" void kernel_launch(void* const* d_in, const int* in_sizes, int n_in,
                              void* d_out, int out_size, void* d_ws, size_t ws_size,
                              hipStream_t stream) {
    const float* x0s = (const float*)d_in[0];
    const float* W1  = (const float*)d_in[1];
    const float* b1  = (const float*)d_in[2];
    const float* W2  = (const float*)d_in[3];
    const float* b2  = (const float*)d_in[4];
    const float* W3  = (const float*)d_in[5];
    const float* b3  = (const float*)d_in[6];
    const void*  Tp  = d_in[7];
    float* out = (float*)d_out;

    const int B = in_sizes[0] / 64;
    const int nwaves = (B + 1) / 2;
    const int grid = (nwaves + WPB - 1) / WPB;

    init_n<<<1, 1, 0, stream>>>(out + (out_size - 1));
    ode_kernel<<<grid, 256, 0, stream>>>(x0s, W1, b1, W2, b2, W3, b3, Tp,
                                         out, out_size, B);
}